// Round 1
// baseline (225.963 us; speedup 1.0000x reference)
//
#include <hip/hip_runtime.h>
#include <math.h>

namespace {
constexpr int COARSE = 32;
constexpr int NATOMS = 16;
constexpr int NPT    = 767;   // N_INT - 1
constexpr int NRAYS  = 256;
constexpr double VOXEL_D = 1.3 * 2.0 / 32.0 / 4.0;
constexpr float  VOXEL_F = (float)VOXEL_D;
constexpr float  STEP_F  = (float)(VOXEL_D / 2.0);
constexpr float  RAD     = 1.3f;
}

__global__ __launch_bounds__(256)
void shdict_render(const float* __restrict__ rays_o,
                   const float* __restrict__ rays_d,
                   const float* __restrict__ grid,
                   const float* __restrict__ atoms,
                   float* __restrict__ out)
{
  const int ray = blockIdx.x;
  const int tid = threadIdx.x;

  __shared__ float s_alpha[NPT];
  __shared__ float s_rgb[NPT][3];

  const float ox = rays_o[ray*3+0], oy = rays_o[ray*3+1], oz = rays_o[ray*3+2];
  const float dx = rays_d[ray*3+0], dy = rays_d[ray*3+1], dz = rays_d[ray*3+2];

  const float m0 = fminf((RAD - ox)/dx, (-RAD - ox)/dx);
  const float m1 = fminf((RAD - oy)/dy, (-RAD - oy)/dy);
  const float m2 = fminf((RAD - oz)/dz, (-RAD - oz)/dz);
  const float start = fmaxf(fmaxf(m0, m1), m2);

  const float dnorm = sqrtf(dx*dx + dy*dy + dz*dz);
  const float inx = dx/dnorm, iny = dy/dnorm, inz = dz/dnorm;
  float sh[9];
  sh[0] = 0.28209479177387814f;
  sh[1] = -0.4886025119029199f*iny;
  sh[2] =  0.4886025119029199f*inz;
  sh[3] = -0.4886025119029199f*inx;
  sh[4] =  1.0925484305920792f*inx*iny;
  sh[5] = -1.0925484305920792f*iny*inz;
  sh[6] =  0.31539156525252005f*(2.0f*inz*inz - inx*inx - iny*iny);
  sh[7] = -1.0925484305920792f*inx*inz;
  sh[8] =  0.5462742152960396f*(inx*inx - iny*iny);

  float* alpha_out = out + NRAYS*3;

  for (int j = tid; j < NPT; j += 256) {
    const float t  = start + (float)j * STEP_F;
    const float px = ox + t*dx;
    const float py = oy + t*dy;
    const float pz = oz + t*dz;
    const bool inb = (px > -RAD) && (px < RAD) && (py > -RAD) && (py < RAD)
                  && (pz > -RAD) && (pz < RAD);
    float a = 0.0f, r0 = 0.5f, r1 = 0.5f, r2 = 0.5f;
    if (inb) {
      const float ux = (px + RAD) / VOXEL_F;
      const float uy = (py + RAD) / VOXEL_F;
      const float uz = (pz + RAD) / VOXEL_F;
      float4 acc4[7];
      #pragma unroll
      for (int q = 0; q < 7; ++q) acc4[q] = make_float4(0.f,0.f,0.f,0.f);

      for (int corner = 0; corner < 8; ++corner) {
        const float sx = (corner & 4) ? 0.5f : -0.5f;
        const float sy = (corner & 2) ? 0.5f : -0.5f;
        const float sz = (corner & 1) ? 0.5f : -0.5f;
        const float pfx = fminf(fmaxf(floorf(ux + sx), 0.0f), 127.0f);
        const float pfy = fminf(fmaxf(floorf(uy + sy), 0.0f), 127.0f);
        const float pfz = fminf(fmaxf(floorf(uz + sz), 0.0f), 127.0f);
        const float fx = fabsf(ux - (pfx + 0.5f));
        const float fy = fabsf(uy - (pfy + 0.5f));
        const float fz = fabsf(uz - (pfz + 0.5f));
        const float w = (1.0f-fx)*(1.0f-fy)*(1.0f-fz);
        const int ix = (int)pfx, iy = (int)pfy, iz = (int)pfz;
        const int cell = ((ix >> 2)*COARSE + (iy >> 2))*COARSE + (iz >> 2);
        const int fine = ((ix & 3)*4 + (iy & 3))*4 + (iz & 3);
        const float4* cv = (const float4*)(grid + (long)cell*448);
        const float4* fv = (const float4*)(atoms + (long)fine*448);
        float4 res[7];
        #pragma unroll
        for (int q = 0; q < 7; ++q) res[q] = make_float4(0.f,0.f,0.f,0.f);
        for (int aa = 0; aa < NATOMS; ++aa) {
          #pragma unroll
          for (int q = 0; q < 7; ++q) {
            const float4 c = cv[aa*7 + q];
            const float4 f = fv[aa*7 + q];
            res[q].x += c.x*f.x;
            res[q].y += c.y*f.y;
            res[q].z += c.z*f.z;
            res[q].w += c.w*f.w;
          }
        }
        #pragma unroll
        for (int q = 0; q < 7; ++q) {
          acc4[q].x += w*res[q].x;
          acc4[q].y += w*res[q].y;
          acc4[q].z += w*res[q].z;
          acc4[q].w += w*res[q].w;
        }
      }
      const float* data = (const float*)acc4;
      const float sigma = fmaxf(data[27], 0.0f);
      const float tnext = start + (float)(j+1) * STEP_F;
      const float dist  = (tnext - t) * dnorm;
      a = 1.0f - expf(-sigma * dist);
      float p0 = 0.f, p1 = 0.f, p2 = 0.f;
      #pragma unroll
      for (int k = 0; k < 9; ++k) {
        p0 += sh[k]*data[k];
        p1 += sh[k]*data[9+k];
        p2 += sh[k]*data[18+k];
      }
      r0 = 1.0f/(1.0f + expf(-p0));
      r1 = 1.0f/(1.0f + expf(-p1));
      r2 = 1.0f/(1.0f + expf(-p2));
    }
    s_alpha[j]  = a;
    s_rgb[j][0] = r0; s_rgb[j][1] = r1; s_rgb[j][2] = r2;
    alpha_out[ray*NPT + j] = a;
  }
  __syncthreads();

  // Phase 2: transmittance scan + outputs, one wave per ray (wave 0 of block)
  if (tid < 64) {
    const int lane = tid;
    float carry = 1.0f;
    float acc = 0.f, dep = 0.f, c0 = 0.f, c1 = 0.f, c2 = 0.f;
    for (int chunk = 0; chunk < 12; ++chunk) {
      const int j = chunk*64 + lane;
      const float a = (j < NPT) ? s_alpha[j] : 0.0f;
      const float v = 1.0f - a + 1e-10f;
      float s = v;
      #pragma unroll
      for (int off = 1; off < 64; off <<= 1) {
        const float o = __shfl_up(s, off, 64);
        if (lane >= off) s *= o;
      }
      float excl = __shfl_up(s, 1, 64);
      if (lane == 0) excl = 1.0f;
      const float T = carry * excl;
      if (j < NPT) {
        const float al = a * T;
        acc += al;
        const float t = start + (float)j * STEP_F;
        dep += al * t;
        c0 += al * s_rgb[j][0];
        c1 += al * s_rgb[j][1];
        c2 += al * s_rgb[j][2];
      }
      carry *= __shfl(s, 63, 64);
    }
    #pragma unroll
    for (int off = 32; off >= 1; off >>= 1) {
      acc += __shfl_down(acc, off, 64);
      dep += __shfl_down(dep, off, 64);
      c0  += __shfl_down(c0,  off, 64);
      c1  += __shfl_down(c1,  off, 64);
      c2  += __shfl_down(c2,  off, 64);
    }
    if (lane == 0) {
      const float bg = 1.0f - acc;
      out[ray*3+0] = c0 + bg;
      out[ray*3+1] = c1 + bg;
      out[ray*3+2] = c2 + bg;
      out[NRAYS*3 + NRAYS*NPT + ray] = dep;
      if (ray == 0) out[NRAYS*3 + NRAYS*NPT + NRAYS] = 0.0f;
    }
  }
}

extern "C" void kernel_launch(void* const* d_in, const int* in_sizes, int n_in,
                              void* d_out, int out_size, void* d_ws, size_t ws_size,
                              hipStream_t stream) {
  const float* rays_o = (const float*)d_in[0];
  const float* rays_d = (const float*)d_in[1];
  const float* grid   = (const float*)d_in[2];
  const float* atoms  = (const float*)d_in[3];
  (void)in_sizes; (void)n_in; (void)out_size; (void)d_ws; (void)ws_size;
  hipLaunchKernelGGL(shdict_render, dim3(NRAYS), dim3(256), 0, stream,
                     rays_o, rays_d, grid, atoms, (float*)d_out);
}